// Round 6
// baseline (1066.767 us; speedup 1.0000x reference)
//
#include <hip/hip_runtime.h>

#define EPS_LEN   1e-20f
#define EPS_DENOM 1e-6f

// ---- tier 1 (chunked, embedded f32 payload) ----
#define CB_LOG   11
#define CB       (1 << CB_LOG)      // 2048 vertices per bucket
#define BLKA     1024
#define MAXB     1024               // max buckets (histogram arrays)
#define NCHUNK   2
#define CAPC     6528               // per-bucket per-chunk capacity (mean 6140, +5 sigma)

// ---- tier 2 (round-3 proven path) ----
#define CB2_LOG  13
#define CB2      (1 << CB2_LOG)
#define MAXB2    256
#define CAP2     57344
#define FST      6
#define QLOG     11
#define QSIZE    (1 << QLOG)

// ===========================================================================
// TIER 1 kernel A: per-face compute + block-coalesced binning of a face chunk.
// Entries embed full f32 payload: en (normal, 12B), et (tangent, 12B), ev u16.
// ===========================================================================
__global__ __launch_bounds__(BLKA)
void vg_face_bin_c(const float* __restrict__ pos, const int* __restrict__ faces,
                   const float* __restrict__ tex, const int* __restrict__ uvf,
                   float* __restrict__ en, float* __restrict__ et,
                   unsigned short* __restrict__ ev,
                   int* __restrict__ cursors, int* __restrict__ validw,
                   float* __restrict__ nacc, float* __restrict__ tacc,
                   int f0, int f1, int NBC)
{
    __shared__ int h[MAXB], sc[MAXB], loff[MAXB], lfill[MAXB], gbase[MAXB];
    __shared__ float spnx[BLKA], spny[BLKA], spnz[BLKA];
    __shared__ float sptx[BLKA], spty[BLKA], sptz[BLKA];
    __shared__ unsigned short sfl[3 * BLKA];
    __shared__ unsigned short svloc[3 * BLKA];
    __shared__ unsigned short sbuck[3 * BLKA];

    const int t = threadIdx.x;
    const int f = f0 + blockIdx.x * BLKA + t;

    h[t] = 0; lfill[t] = 0;                    // t spans 0..1023 == MAXB
    for (int i = t; i < 3 * BLKA; i += BLKA) sbuck[i] = 0xFFFFu;
    __syncthreads();

    const bool on = (f < f1);
    int i0 = 0, i1 = 0, i2 = 0;
    float nx = 0, ny = 0, nz = 0, txv = 0, tyv = 0, tzv = 0;

    if (on) {
        i0 = faces[3 * f + 0]; i1 = faces[3 * f + 1]; i2 = faces[3 * f + 2];

        const float p0x = pos[3*i0+0], p0y = pos[3*i0+1], p0z = pos[3*i0+2];
        const float p1x = pos[3*i1+0], p1y = pos[3*i1+1], p1z = pos[3*i1+2];
        const float p2x = pos[3*i2+0], p2y = pos[3*i2+1], p2z = pos[3*i2+2];

        const float e1x = p1x - p0x, e1y = p1y - p0y, e1z = p1z - p0z;
        const float e2x = p2x - p0x, e2y = p2y - p0y, e2z = p2z - p0z;

        nx = e1y * e2z - e1z * e2y;
        ny = e1z * e2x - e1x * e2z;
        nz = e1x * e2y - e1y * e2x;

        const int t0 = uvf[3 * f + 0];
        const int t1 = uvf[3 * f + 1];
        const int t2 = uvf[3 * f + 2];

        const float u0x = tex[2*t0+0], u0y = tex[2*t0+1];
        const float u1x = tex[2*t1+0], u1y = tex[2*t1+1];
        const float u2x = tex[2*t2+0], u2y = tex[2*t2+1];

        const float d1x = u1x - u0x, d1y = u1y - u0y;
        const float d2x = u2x - u0x, d2y = u2y - u0y;

        float denom = d1x * d2y - d1y * d2x;
        denom = (denom > 0.0f) ? fmaxf(denom, EPS_DENOM) : fminf(denom, -EPS_DENOM);
        const float inv = 1.0f / denom;

        txv = (e1x * d2y - e2x * d1y) * inv;
        tyv = (e1y * d2y - e2y * d1y) * inv;
        tzv = (e1z * d2y - e2z * d1y) * inv;

        spnx[t] = nx;  spny[t] = ny;  spnz[t] = nz;
        sptx[t] = txv; spty[t] = tyv; sptz[t] = tzv;

        atomicAdd(&h[i0 >> CB_LOG], 1);
        atomicAdd(&h[i1 >> CB_LOG], 1);
        atomicAdd(&h[i2 >> CB_LOG], 1);
    }
    __syncthreads();

    // exclusive scan over MAXB (Hillis-Steele), blockDim == MAXB
    sc[t] = h[t];
    __syncthreads();
    for (int d = 1; d < MAXB; d <<= 1) {
        const int v2 = sc[t] + ((t >= d) ? sc[t - d] : 0);
        __syncthreads();
        sc[t] = v2;
        __syncthreads();
    }
    {
        loff[t] = sc[t] - h[t];
        const int cnt = h[t];
        int gb = -1;
        if (t < NBC && cnt > 0) {
            gb = atomicAdd(&cursors[t], cnt);
            if (gb + cnt <= CAPC) atomicMax(&validw[t], gb + cnt);
            else gb = -1;                      // whole chunklet falls back
        }
        gbase[t] = gb;
    }
    __syncthreads();

    if (on) {
        const int vi[3] = { i0, i1, i2 };
#pragma unroll
        for (int c = 0; c < 3; ++c) {
            const int v = vi[c];
            const int b = v >> CB_LOG;
            if (gbase[b] >= 0) {
                const int slot = atomicAdd(&lfill[b], 1);
                const int p = loff[b] + slot;
                sfl[p]   = (unsigned short)t;
                svloc[p] = (unsigned short)(v & (CB - 1));
                sbuck[p] = (unsigned short)b;
            } else {
                atomicAdd(&nacc[3*v+0], nx);
                atomicAdd(&nacc[3*v+1], ny);
                atomicAdd(&nacc[3*v+2], nz);
                atomicAdd(&tacc[3*v+0], txv);
                atomicAdd(&tacc[3*v+1], tyv);
                atomicAdd(&tacc[3*v+2], tzv);
            }
        }
    }
    __syncthreads();

    // coalesced copy-out: consecutive i in a bucket -> consecutive slots
    for (int i = t; i < 3 * BLKA; i += BLKA) {
        const unsigned b = sbuck[i];
        if (b != 0xFFFFu) {
            const int g = gbase[b] + (i - loff[b]);
            const size_t s = (size_t)b * CAPC + g;
            const int fl = sfl[i];
            en[s*3+0] = spnx[fl]; en[s*3+1] = spny[fl]; en[s*3+2] = spnz[fl];
            et[s*3+0] = sptx[fl]; et[s*3+1] = spty[fl]; et[s*3+2] = sptz[fl];
            ev[s] = svloc[i];
        }
    }
}

// ===========================================================================
// TIER 1 kernel B: one block per bucket, single pass, both payloads in 48KB
// LDS. Non-final chunk: add to global accumulators (exclusive per block, no
// atomics). Final chunk: add + fused finalize.
// ===========================================================================
__global__ __launch_bounds__(BLKA)
void vg_reduce_c(const float* __restrict__ en, const float* __restrict__ et,
                 const unsigned short* __restrict__ ev,
                 const int* __restrict__ validw,
                 float* __restrict__ nacc, float* __restrict__ tacc,
                 int V, int isFinal)
{
    __shared__ float accn[CB * 3];   // 24 KB
    __shared__ float acct[CB * 3];   // 24 KB
    const int b = blockIdx.x;
    const int t = threadIdx.x;

    for (int i = t; i < CB * 3; i += BLKA) { accn[i] = 0.0f; acct[i] = 0.0f; }
    __syncthreads();

    int count = validw[b];
    if (count > CAPC) count = CAPC;
    const size_t ebase = (size_t)b * CAPC;

    for (int e = t; e < count; e += BLKA) {
        const int vloc = (int)ev[ebase + e];
        const float* pn = &en[(ebase + e) * 3];
        const float* pt = &et[(ebase + e) * 3];
        float* an = &accn[vloc * 3];
        float* at = &acct[vloc * 3];
        atomicAdd(an + 0, pn[0]);
        atomicAdd(an + 1, pn[1]);
        atomicAdd(an + 2, pn[2]);
        atomicAdd(at + 0, pt[0]);
        atomicAdd(at + 1, pt[1]);
        atomicAdd(at + 2, pt[2]);
    }
    __syncthreads();

    const int vbase = b << CB_LOG;
#pragma unroll
    for (int k = 0; k < CB; k += BLKA) {
        const int i = t + k;
        const int v = vbase + i;
        if (v < V) {
            float nx = nacc[3*v+0] + accn[3*i+0];
            float ny = nacc[3*v+1] + accn[3*i+1];
            float nz = nacc[3*v+2] + accn[3*i+2];
            float tx = tacc[3*v+0] + acct[3*i+0];
            float ty = tacc[3*v+1] + acct[3*i+1];
            float tz = tacc[3*v+2] + acct[3*i+2];

            if (isFinal) {
                const float nd = nx*nx + ny*ny + nz*nz;
                if (nd > EPS_LEN) {
                    const float invn = 1.0f / sqrtf(nd);
                    nx *= invn; ny *= invn; nz *= invn;
                } else {
                    nx = 0.0f; ny = 0.0f; nz = 1.0f;
                }

                const float td = tx*tx + ty*ty + tz*tz;
                const float invt = 1.0f / sqrtf(fmaxf(td, EPS_LEN));
                tx *= invt; ty *= invt; tz *= invt;

                const float dp = tx*nx + ty*ny + tz*nz;
                tx -= dp * nx; ty -= dp * ny; tz -= dp * nz;

                const float td2 = tx*tx + ty*ty + tz*tz;
                const float invt2 = 1.0f / sqrtf(fmaxf(td2, EPS_LEN));
                tx *= invt2; ty *= invt2; tz *= invt2;
            }

            nacc[3*v+0] = nx; nacc[3*v+1] = ny; nacc[3*v+2] = nz;
            tacc[3*v+0] = tx; tacc[3*v+1] = ty; tacc[3*v+2] = tz;
        }
    }
}

// ===========================================================================
// TIER 2: round-3 proven path (face-record gather).
// ===========================================================================
__global__ __launch_bounds__(BLKA)
void vg_face_bin3(const float* __restrict__ pos, const int* __restrict__ faces,
                  const float* __restrict__ tex, const int* __restrict__ uvf,
                  float* __restrict__ face_data,
                  unsigned* __restrict__ ef, unsigned short* __restrict__ ev,
                  int* __restrict__ cursors, int* __restrict__ validw,
                  float* __restrict__ nacc, float* __restrict__ tacc,
                  int F, int NBC)
{
    __shared__ int h[MAXB2], sc[MAXB2], loff[MAXB2], lfill[MAXB2], gbase[MAXB2];
    __shared__ unsigned       sface[3 * BLKA];
    __shared__ unsigned short svloc[3 * BLKA];
    __shared__ unsigned char  sbuck[3 * BLKA];

    const int t = threadIdx.x;
    const int f = blockIdx.x * BLKA + t;

    if (t < MAXB2) { h[t] = 0; lfill[t] = 0; }
    for (int i = t; i < 3 * BLKA; i += BLKA) sbuck[i] = 0xFF;
    __syncthreads();

    const bool on = (f < F);
    int i0 = 0, i1 = 0, i2 = 0;
    float nx = 0, ny = 0, nz = 0, txv = 0, tyv = 0, tzv = 0;

    if (on) {
        i0 = faces[3 * f + 0]; i1 = faces[3 * f + 1]; i2 = faces[3 * f + 2];

        const float p0x = pos[3*i0+0], p0y = pos[3*i0+1], p0z = pos[3*i0+2];
        const float p1x = pos[3*i1+0], p1y = pos[3*i1+1], p1z = pos[3*i1+2];
        const float p2x = pos[3*i2+0], p2y = pos[3*i2+1], p2z = pos[3*i2+2];

        const float e1x = p1x - p0x, e1y = p1y - p0y, e1z = p1z - p0z;
        const float e2x = p2x - p0x, e2y = p2y - p0y, e2z = p2z - p0z;

        nx = e1y * e2z - e1z * e2y;
        ny = e1z * e2x - e1x * e2z;
        nz = e1x * e2y - e1y * e2x;

        const int t0 = uvf[3 * f + 0];
        const int t1 = uvf[3 * f + 1];
        const int t2 = uvf[3 * f + 2];

        const float u0x = tex[2*t0+0], u0y = tex[2*t0+1];
        const float u1x = tex[2*t1+0], u1y = tex[2*t1+1];
        const float u2x = tex[2*t2+0], u2y = tex[2*t2+1];

        const float d1x = u1x - u0x, d1y = u1y - u0y;
        const float d2x = u2x - u0x, d2y = u2y - u0y;

        float denom = d1x * d2y - d1y * d2x;
        denom = (denom > 0.0f) ? fmaxf(denom, EPS_DENOM) : fminf(denom, -EPS_DENOM);
        const float inv = 1.0f / denom;

        txv = (e1x * d2y - e2x * d1y) * inv;
        tyv = (e1y * d2y - e2y * d1y) * inv;
        tzv = (e1z * d2y - e2z * d1y) * inv;

        float* fd = &face_data[(size_t)f * FST];
        reinterpret_cast<float2*>(fd)[0] = make_float2(nx, ny);
        reinterpret_cast<float2*>(fd)[1] = make_float2(nz, txv);
        reinterpret_cast<float2*>(fd)[2] = make_float2(tyv, tzv);

        atomicAdd(&h[i0 >> CB2_LOG], 1);
        atomicAdd(&h[i1 >> CB2_LOG], 1);
        atomicAdd(&h[i2 >> CB2_LOG], 1);
    }
    __syncthreads();

    if (t < MAXB2) sc[t] = h[t];
    __syncthreads();
    for (int d = 1; d < MAXB2; d <<= 1) {
        int v2 = 0;
        if (t < MAXB2) v2 = sc[t] + ((t >= d) ? sc[t - d] : 0);
        __syncthreads();
        if (t < MAXB2) sc[t] = v2;
        __syncthreads();
    }
    if (t < MAXB2) {
        loff[t] = sc[t] - h[t];
        const int cnt = h[t];
        int gb = -1;
        if (t < NBC && cnt > 0) {
            gb = atomicAdd(&cursors[t], cnt);
            if (gb + cnt <= CAP2) atomicMax(&validw[t], gb + cnt);
            else gb = -1;
        }
        gbase[t] = gb;
    }
    __syncthreads();

    if (on) {
        const int vi[3] = { i0, i1, i2 };
#pragma unroll
        for (int c = 0; c < 3; ++c) {
            const int v = vi[c];
            const int b = v >> CB2_LOG;
            if (gbase[b] >= 0) {
                const int slot = atomicAdd(&lfill[b], 1);
                const int p = loff[b] + slot;
                sface[p] = (unsigned)f;
                svloc[p] = (unsigned short)(v & (CB2 - 1));
                sbuck[p] = (unsigned char)b;
            } else {
                atomicAdd(&nacc[3*v+0], nx);
                atomicAdd(&nacc[3*v+1], ny);
                atomicAdd(&nacc[3*v+2], nz);
                atomicAdd(&tacc[3*v+0], txv);
                atomicAdd(&tacc[3*v+1], tyv);
                atomicAdd(&tacc[3*v+2], tzv);
            }
        }
    }
    __syncthreads();

    for (int i = t; i < 3 * BLKA; i += BLKA) {
        const unsigned b = sbuck[i];
        if (b != 0xFFu) {
            const int g = gbase[b] + (i - loff[b]);
            const size_t base = (size_t)b * CAP2;
            ef[base + g] = sface[i];
            ev[base + g] = svloc[i];
        }
    }
}

__global__ __launch_bounds__(BLKA)
void vg_bucket_reduce3(const float* __restrict__ face_data,
                       const unsigned* __restrict__ ef,
                       const unsigned short* __restrict__ ev,
                       const int* __restrict__ validw,
                       float* __restrict__ nacc, float* __restrict__ tacc,
                       int V)
{
    __shared__ float acc[QSIZE * 6];   // 48 KB
    const int b = blockIdx.x;
    const int t = threadIdx.x;
    int count = validw[b];
    if (count > CAP2) count = CAP2;
    const size_t ebase = (size_t)b * CAP2;
    const int vbase = b << CB2_LOG;

    for (int q = 0; q < 4; ++q) {
        for (int i = t; i < QSIZE * 6; i += BLKA) acc[i] = 0.0f;
        __syncthreads();

        for (int e = t; e < count; e += BLKA) {
            const int vloc = (int)ev[ebase + e];
            if ((vloc >> QLOG) == q) {
                const unsigned f = ef[ebase + e];
                const float* fd = &face_data[(size_t)f * FST];
                const float2 a0 = reinterpret_cast<const float2*>(fd)[0];
                const float2 a1 = reinterpret_cast<const float2*>(fd)[1];
                const float2 a2 = reinterpret_cast<const float2*>(fd)[2];
                float* a = &acc[(vloc & (QSIZE - 1)) * 6];
                atomicAdd(a + 0, a0.x);
                atomicAdd(a + 1, a0.y);
                atomicAdd(a + 2, a1.x);
                atomicAdd(a + 3, a1.y);
                atomicAdd(a + 4, a2.x);
                atomicAdd(a + 5, a2.y);
            }
        }
        __syncthreads();

        for (int i = t; i < QSIZE; i += BLKA) {
            const int v = vbase + (q << QLOG) + i;
            if (v < V) {
                float nx = nacc[3*v+0] + acc[i*6+0];
                float ny = nacc[3*v+1] + acc[i*6+1];
                float nz = nacc[3*v+2] + acc[i*6+2];
                float tx = tacc[3*v+0] + acc[i*6+3];
                float ty = tacc[3*v+1] + acc[i*6+4];
                float tz = tacc[3*v+2] + acc[i*6+5];

                const float nd = nx*nx + ny*ny + nz*nz;
                if (nd > EPS_LEN) {
                    const float invn = 1.0f / sqrtf(nd);
                    nx *= invn; ny *= invn; nz *= invn;
                } else {
                    nx = 0.0f; ny = 0.0f; nz = 1.0f;
                }

                const float td = tx*tx + ty*ty + tz*tz;
                const float invt = 1.0f / sqrtf(fmaxf(td, EPS_LEN));
                tx *= invt; ty *= invt; tz *= invt;

                const float dp = tx*nx + ty*ny + tz*nz;
                tx -= dp * nx; ty -= dp * ny; tz -= dp * nz;

                const float td2 = tx*tx + ty*ty + tz*tz;
                const float invt2 = 1.0f / sqrtf(fmaxf(td2, EPS_LEN));
                tx *= invt2; ty *= invt2; tz *= invt2;

                nacc[3*v+0] = nx; nacc[3*v+1] = ny; nacc[3*v+2] = nz;
                tacc[3*v+0] = tx; tacc[3*v+1] = ty; tacc[3*v+2] = tz;
            }
        }
        __syncthreads();
    }
}

// ===========================================================================
// TIER 3: global-atomic fallback.
// ===========================================================================
__global__ void vg_face_kernel(const float* __restrict__ pos,
                               const int*   __restrict__ faces,
                               const float* __restrict__ tex,
                               const int*   __restrict__ uvf,
                               float* __restrict__ nacc,
                               float* __restrict__ tacc,
                               int F) {
    int f = blockIdx.x * blockDim.x + threadIdx.x;
    if (f >= F) return;

    const int i0 = faces[3*f+0], i1 = faces[3*f+1], i2 = faces[3*f+2];

    const float p0x = pos[3*i0+0], p0y = pos[3*i0+1], p0z = pos[3*i0+2];
    const float p1x = pos[3*i1+0], p1y = pos[3*i1+1], p1z = pos[3*i1+2];
    const float p2x = pos[3*i2+0], p2y = pos[3*i2+1], p2z = pos[3*i2+2];

    const float e1x = p1x - p0x, e1y = p1y - p0y, e1z = p1z - p0z;
    const float e2x = p2x - p0x, e2y = p2y - p0y, e2z = p2z - p0z;

    const float nx = e1y*e2z - e1z*e2y;
    const float ny = e1z*e2x - e1x*e2z;
    const float nz = e1x*e2y - e1y*e2x;

    const int t0 = uvf[3*f+0], t1 = uvf[3*f+1], t2 = uvf[3*f+2];

    const float u0x = tex[2*t0+0], u0y = tex[2*t0+1];
    const float u1x = tex[2*t1+0], u1y = tex[2*t1+1];
    const float u2x = tex[2*t2+0], u2y = tex[2*t2+1];

    const float d1x = u1x - u0x, d1y = u1y - u0y;
    const float d2x = u2x - u0x, d2y = u2y - u0y;

    float denom = d1x * d2y - d1y * d2x;
    denom = (denom > 0.0f) ? fmaxf(denom, EPS_DENOM) : fminf(denom, -EPS_DENOM);
    const float inv = 1.0f / denom;

    const float tx = (e1x*d2y - e2x*d1y) * inv;
    const float ty = (e1y*d2y - e2y*d1y) * inv;
    const float tz = (e1z*d2y - e2z*d1y) * inv;

    atomicAdd(&nacc[3*i0+0], nx); atomicAdd(&nacc[3*i0+1], ny); atomicAdd(&nacc[3*i0+2], nz);
    atomicAdd(&nacc[3*i1+0], nx); atomicAdd(&nacc[3*i1+1], ny); atomicAdd(&nacc[3*i1+2], nz);
    atomicAdd(&nacc[3*i2+0], nx); atomicAdd(&nacc[3*i2+1], ny); atomicAdd(&nacc[3*i2+2], nz);
    atomicAdd(&tacc[3*i0+0], tx); atomicAdd(&tacc[3*i0+1], ty); atomicAdd(&tacc[3*i0+2], tz);
    atomicAdd(&tacc[3*i1+0], tx); atomicAdd(&tacc[3*i1+1], ty); atomicAdd(&tacc[3*i1+2], tz);
    atomicAdd(&tacc[3*i2+0], tx); atomicAdd(&tacc[3*i2+1], ty); atomicAdd(&tacc[3*i2+2], tz);
}

__global__ void vg_finalize_kernel(float* __restrict__ nacc,
                                   float* __restrict__ tacc,
                                   int V) {
    int v = blockIdx.x * blockDim.x + threadIdx.x;
    if (v >= V) return;

    float nx = nacc[3*v+0], ny = nacc[3*v+1], nz = nacc[3*v+2];
    float nd = nx*nx + ny*ny + nz*nz;
    if (nd > EPS_LEN) {
        const float invn = 1.0f / sqrtf(nd);
        nx *= invn; ny *= invn; nz *= invn;
    } else {
        nx = 0.0f; ny = 0.0f; nz = 1.0f;
    }

    float tx = tacc[3*v+0], ty = tacc[3*v+1], tz = tacc[3*v+2];
    float td = tx*tx + ty*ty + tz*tz;
    float invt = 1.0f / sqrtf(fmaxf(td, EPS_LEN));
    tx *= invt; ty *= invt; tz *= invt;
    const float dp = tx*nx + ty*ny + tz*nz;
    tx -= dp*nx; ty -= dp*ny; tz -= dp*nz;
    float td2 = tx*tx + ty*ty + tz*tz;
    float invt2 = 1.0f / sqrtf(fmaxf(td2, EPS_LEN));
    tx *= invt2; ty *= invt2; tz *= invt2;

    nacc[3*v+0] = nx; nacc[3*v+1] = ny; nacc[3*v+2] = nz;
    tacc[3*v+0] = tx; tacc[3*v+1] = ty; tacc[3*v+2] = tz;
}

extern "C" void kernel_launch(void* const* d_in, const int* in_sizes, int n_in,
                              void* d_out, int out_size, void* d_ws, size_t ws_size,
                              hipStream_t stream) {
    const float* pos   = (const float*)d_in[0];
    const int*   faces = (const int*)  d_in[1];
    const float* tex   = (const float*)d_in[2];
    const int*   uvf   = (const int*)  d_in[3];

    const int V = in_sizes[0] / 3;
    const int F = in_sizes[1] / 3;

    float* out  = (float*)d_out;
    float* nacc = out;
    float* tacc = out + (size_t)3 * V;

    hipMemsetAsync(d_out, 0, (size_t)out_size * sizeof(float), stream);

    // ---- tier 1: chunked embedded-f32 payload ----
    const int NBC1 = (V + CB - 1) >> CB_LOG;
    {
        const size_t NE1   = (size_t)NBC1 * CAPC;
        const size_t en_b  = (NE1 * 12 + 255) & ~(size_t)255;
        const size_t et_b  = (NE1 * 12 + 255) & ~(size_t)255;
        const size_t ev_b  = (NE1 * 2 + 255) & ~(size_t)255;
        const size_t cur_b = ((size_t)NBC1 * sizeof(int) + 255) & ~(size_t)255;
        const size_t need1 = en_b + et_b + ev_b + 2 * cur_b + 256;

        if (ws_size >= need1 && NBC1 <= MAXB) {
            char* ws = (char*)d_ws;
            float*          en  = (float*)ws;          ws += en_b;
            float*          et  = (float*)ws;          ws += et_b;
            unsigned short* ev  = (unsigned short*)ws; ws += ev_b;
            int*            cursors = (int*)ws;        ws += cur_b;
            int*            validw  = (int*)ws;

            const int Fc = (F + NCHUNK - 1) / NCHUNK;
            for (int c = 0; c < NCHUNK; ++c) {
                const int f0 = c * Fc;
                const int f1 = (f0 + Fc < F) ? (f0 + Fc) : F;
                if (f0 >= f1) continue;

                hipMemsetAsync(cursors, 0, cur_b, stream);
                hipMemsetAsync(validw,  0, cur_b, stream);

                const int nblk = (f1 - f0 + BLKA - 1) / BLKA;
                vg_face_bin_c<<<nblk, BLKA, 0, stream>>>(
                    pos, faces, tex, uvf, en, et, ev, cursors, validw,
                    nacc, tacc, f0, f1, NBC1);

                const int isFinal = (f1 == F) ? 1 : 0;
                vg_reduce_c<<<NBC1, BLKA, 0, stream>>>(
                    en, et, ev, validw, nacc, tacc, V, isFinal);
            }
            return;
        }
    }

    // ---- tier 2: round-3 face-record gather ----
    const int NBC2 = (V + CB2 - 1) >> CB2_LOG;
    {
        const size_t NE2    = (size_t)NBC2 * CAP2;
        const size_t face_b = ((size_t)F * FST * sizeof(float) + 255) & ~(size_t)255;
        const size_t ef_b   = (NE2 * 4 + 255) & ~(size_t)255;
        const size_t ev2_b  = (NE2 * 2 + 255) & ~(size_t)255;
        const size_t cur_b  = ((size_t)NBC2 * sizeof(int) + 255) & ~(size_t)255;
        const size_t need2  = face_b + ef_b + ev2_b + 2 * cur_b + 256;

        if (ws_size >= need2 && NBC2 <= 255 && F < (1 << 22)) {
            char* ws = (char*)d_ws;
            float*          face_data = (float*)ws;          ws += face_b;
            unsigned*       ef        = (unsigned*)ws;       ws += ef_b;
            unsigned short* ev        = (unsigned short*)ws; ws += ev2_b;
            int*            cursors   = (int*)ws;            ws += cur_b;
            int*            validw    = (int*)ws;

            hipMemsetAsync(cursors, 0, cur_b, stream);
            hipMemsetAsync(validw,  0, cur_b, stream);

            vg_face_bin3<<<(F + BLKA - 1) / BLKA, BLKA, 0, stream>>>(
                pos, faces, tex, uvf, face_data, ef, ev, cursors, validw,
                nacc, tacc, F, NBC2);
            vg_bucket_reduce3<<<NBC2, BLKA, 0, stream>>>(
                face_data, ef, ev, validw, nacc, tacc, V);
            return;
        }
    }

    // ---- tier 3: global atomics ----
    const int BLK = 256;
    vg_face_kernel<<<(F + BLK - 1) / BLK, BLK, 0, stream>>>(pos, faces, tex, uvf,
                                                            nacc, tacc, F);
    vg_finalize_kernel<<<(V + BLK - 1) / BLK, BLK, 0, stream>>>(nacc, tacc, V);
}

// Round 7
// 920.091 us; speedup vs baseline: 1.1594x; 1.1594x over previous
//
#include <hip/hip_runtime.h>

#define EPS_LEN   1e-20f
#define EPS_DENOM 1e-6f

#define BLKA     1024

// ---- tier 1: fine buckets, packed u32 entries, face-record gather ----
#define CBF_LOG  10
#define CBF      (1 << CBF_LOG)     // 1024 vertices per bucket
#define NBCP     2048               // padded histogram size (2 per thread)
#define CAPF     7168               // per-bucket capacity (mean ~6271, +11 sigma)
#define FST      6                  // face record floats (24B)

// ---- tier 2 (round-3 proven path) ----
#define CB2_LOG  13
#define CB2      (1 << CB2_LOG)
#define MAXB2    256
#define CAP2     57344
#define QLOG     11
#define QSIZE    (1 << QLOG)

// ===========================================================================
// TIER 1 kernel A: per-face compute, face-record write, block-coalesced
// binning into 1954 fine buckets. Entry = (vloc<<22)|face  (u32).
// ===========================================================================
__global__ __launch_bounds__(BLKA)
void vg_face_bin_f(const float* __restrict__ pos, const int* __restrict__ faces,
                   const float* __restrict__ tex, const int* __restrict__ uvf,
                   float* __restrict__ face_data, unsigned* __restrict__ E,
                   int* __restrict__ cursors, int* __restrict__ validw,
                   float* __restrict__ nacc, float* __restrict__ tacc,
                   int F, int NBC)
{
    __shared__ int h[NBCP];        // histogram -> later gbase
    __shared__ int s0[NBCP];       // scan ping
    __shared__ int s1[NBCP];       // scan pong -> later loff
    __shared__ int lfill[NBCP];
    __shared__ unsigned       spack[3 * BLKA];
    __shared__ unsigned short sbuck[3 * BLKA];

    const int t = threadIdx.x;
    const int f = blockIdx.x * BLKA + t;

    h[t] = 0; h[t + 1024] = 0;
    lfill[t] = 0; lfill[t + 1024] = 0;
    for (int i = t; i < 3 * BLKA; i += BLKA) sbuck[i] = 0xFFFFu;
    __syncthreads();

    const bool on = (f < F);
    int i0 = 0, i1 = 0, i2 = 0;
    float nx = 0, ny = 0, nz = 0, txv = 0, tyv = 0, tzv = 0;

    if (on) {
        i0 = faces[3 * f + 0]; i1 = faces[3 * f + 1]; i2 = faces[3 * f + 2];

        const float p0x = pos[3*i0+0], p0y = pos[3*i0+1], p0z = pos[3*i0+2];
        const float p1x = pos[3*i1+0], p1y = pos[3*i1+1], p1z = pos[3*i1+2];
        const float p2x = pos[3*i2+0], p2y = pos[3*i2+1], p2z = pos[3*i2+2];

        const float e1x = p1x - p0x, e1y = p1y - p0y, e1z = p1z - p0z;
        const float e2x = p2x - p0x, e2y = p2y - p0y, e2z = p2z - p0z;

        nx = e1y * e2z - e1z * e2y;
        ny = e1z * e2x - e1x * e2z;
        nz = e1x * e2y - e1y * e2x;

        const int t0 = uvf[3 * f + 0];
        const int t1 = uvf[3 * f + 1];
        const int t2 = uvf[3 * f + 2];

        const float u0x = tex[2*t0+0], u0y = tex[2*t0+1];
        const float u1x = tex[2*t1+0], u1y = tex[2*t1+1];
        const float u2x = tex[2*t2+0], u2y = tex[2*t2+1];

        const float d1x = u1x - u0x, d1y = u1y - u0y;
        const float d2x = u2x - u0x, d2y = u2y - u0y;

        float denom = d1x * d2y - d1y * d2x;
        denom = (denom > 0.0f) ? fmaxf(denom, EPS_DENOM) : fminf(denom, -EPS_DENOM);
        const float inv = 1.0f / denom;

        txv = (e1x * d2y - e2x * d1y) * inv;
        tyv = (e1y * d2y - e2y * d1y) * inv;
        tzv = (e1z * d2y - e2z * d1y) * inv;

        float* fd = &face_data[(size_t)f * FST];
        reinterpret_cast<float2*>(fd)[0] = make_float2(nx, ny);
        reinterpret_cast<float2*>(fd)[1] = make_float2(nz, txv);
        reinterpret_cast<float2*>(fd)[2] = make_float2(tyv, tzv);

        atomicAdd(&h[i0 >> CBF_LOG], 1);
        atomicAdd(&h[i1 >> CBF_LOG], 1);
        atomicAdd(&h[i2 >> CBF_LOG], 1);
    }
    __syncthreads();

    // inclusive scan over NBCP=2048 with 1024 threads (2 elems/thread),
    // ping-pong Hillis-Steele
    s0[t] = h[t]; s0[t + 1024] = h[t + 1024];
    __syncthreads();
    int* src = s0; int* dst = s1;
    for (int d = 1; d < NBCP; d <<= 1) {
        dst[t] = src[t] + ((t >= d) ? src[t - d] : 0);
        const int k = t + 1024;
        dst[k] = src[k] + ((k >= d) ? src[k - d] : 0);
        __syncthreads();
        int* tmp = src; src = dst; dst = tmp;
    }
    // src = inclusive scan; dst free -> loff; h -> gbase
    int* loffp  = dst;
    int* gbasep = h;
    for (int k = t; k < NBCP; k += 1024) {
        const int incl = src[k];
        const int cnt  = h[k];
        const int lo   = incl - cnt;
        int gb = -1;
        if (k < NBC && cnt > 0) {
            gb = atomicAdd(&cursors[k], cnt);
            if (gb + cnt <= CAPF) atomicMax(&validw[k], gb + cnt);
            else gb = -1;                      // whole chunk falls back
        }
        loffp[k]  = lo;
        gbasep[k] = gb;
    }
    __syncthreads();

    if (on) {
        const int vi[3] = { i0, i1, i2 };
#pragma unroll
        for (int c = 0; c < 3; ++c) {
            const int v = vi[c];
            const int b = v >> CBF_LOG;
            if (gbasep[b] >= 0) {
                const int slot = atomicAdd(&lfill[b], 1);
                const int p = loffp[b] + slot;
                spack[p] = ((unsigned)(v & (CBF - 1)) << 22) | (unsigned)f;
                sbuck[p] = (unsigned short)b;
            } else {
                atomicAdd(&nacc[3*v+0], nx);
                atomicAdd(&nacc[3*v+1], ny);
                atomicAdd(&nacc[3*v+2], nz);
                atomicAdd(&tacc[3*v+0], txv);
                atomicAdd(&tacc[3*v+1], tyv);
                atomicAdd(&tacc[3*v+2], tzv);
            }
        }
    }
    __syncthreads();

    // coalesced copy-out: consecutive i in one bucket -> consecutive slots
    for (int i = t; i < 3 * BLKA; i += BLKA) {
        const unsigned b = sbuck[i];
        if (b != 0xFFFFu) {
            const int g = gbasep[b] + (i - loffp[b]);
            E[(size_t)b * CAPF + g] = spack[i];
        }
    }
}

// ===========================================================================
// TIER 1 kernel B: one block per fine bucket (512 thr, 24KB LDS -> 4 blk/CU,
// full 32-wave occupancy). Single pass over packed entries, gather 24B face
// records, LDS fp atomics, fused finalize.
// ===========================================================================
__global__ __launch_bounds__(512)
void vg_gather_reduce_f(const float* __restrict__ face_data,
                        const unsigned* __restrict__ E,
                        const int* __restrict__ validw,
                        float* __restrict__ nacc, float* __restrict__ tacc,
                        int V)
{
    __shared__ float accn[CBF * 3];   // 12 KB
    __shared__ float acct[CBF * 3];   // 12 KB
    const int b = blockIdx.x;
    const int t = threadIdx.x;

    for (int i = t; i < CBF * 3; i += 512) { accn[i] = 0.0f; acct[i] = 0.0f; }
    __syncthreads();

    int count = validw[b];
    if (count > CAPF) count = CAPF;
    const size_t ebase = (size_t)b * CAPF;

    for (int e = t; e < count; e += 512) {
        const unsigned ent = E[ebase + e];
        const int f    = (int)(ent & 0x3FFFFFu);
        const int vloc = (int)(ent >> 22);
        const float* fd = &face_data[(size_t)f * FST];
        const float2 a0 = reinterpret_cast<const float2*>(fd)[0];
        const float2 a1 = reinterpret_cast<const float2*>(fd)[1];
        const float2 a2 = reinterpret_cast<const float2*>(fd)[2];
        float* an = &accn[vloc * 3];
        float* at = &acct[vloc * 3];
        atomicAdd(an + 0, a0.x);
        atomicAdd(an + 1, a0.y);
        atomicAdd(an + 2, a1.x);
        atomicAdd(at + 0, a1.y);
        atomicAdd(at + 1, a2.x);
        atomicAdd(at + 2, a2.y);
    }
    __syncthreads();

    const int vbase = b << CBF_LOG;
#pragma unroll
    for (int k = 0; k < CBF; k += 512) {
        const int i = t + k;
        const int v = vbase + i;
        if (v < V) {
            float nx = nacc[3*v+0] + accn[3*i+0];
            float ny = nacc[3*v+1] + accn[3*i+1];
            float nz = nacc[3*v+2] + accn[3*i+2];
            float tx = tacc[3*v+0] + acct[3*i+0];
            float ty = tacc[3*v+1] + acct[3*i+1];
            float tz = tacc[3*v+2] + acct[3*i+2];

            const float nd = nx*nx + ny*ny + nz*nz;
            if (nd > EPS_LEN) {
                const float invn = 1.0f / sqrtf(nd);
                nx *= invn; ny *= invn; nz *= invn;
            } else {
                nx = 0.0f; ny = 0.0f; nz = 1.0f;
            }

            const float td = tx*tx + ty*ty + tz*tz;
            const float invt = 1.0f / sqrtf(fmaxf(td, EPS_LEN));
            tx *= invt; ty *= invt; tz *= invt;

            const float dp = tx*nx + ty*ny + tz*nz;
            tx -= dp * nx; ty -= dp * ny; tz -= dp * nz;

            const float td2 = tx*tx + ty*ty + tz*tz;
            const float invt2 = 1.0f / sqrtf(fmaxf(td2, EPS_LEN));
            tx *= invt2; ty *= invt2; tz *= invt2;

            nacc[3*v+0] = nx; nacc[3*v+1] = ny; nacc[3*v+2] = nz;
            tacc[3*v+0] = tx; tacc[3*v+1] = ty; tacc[3*v+2] = tz;
        }
    }
}

// ===========================================================================
// TIER 2: round-3 proven path (coarse buckets, 4-pass reduce).
// ===========================================================================
__global__ __launch_bounds__(BLKA)
void vg_face_bin3(const float* __restrict__ pos, const int* __restrict__ faces,
                  const float* __restrict__ tex, const int* __restrict__ uvf,
                  float* __restrict__ face_data,
                  unsigned* __restrict__ ef, unsigned short* __restrict__ ev,
                  int* __restrict__ cursors, int* __restrict__ validw,
                  float* __restrict__ nacc, float* __restrict__ tacc,
                  int F, int NBC)
{
    __shared__ int h[MAXB2], sc[MAXB2], loff[MAXB2], lfill[MAXB2], gbase[MAXB2];
    __shared__ unsigned       sface[3 * BLKA];
    __shared__ unsigned short svloc[3 * BLKA];
    __shared__ unsigned char  sbuck[3 * BLKA];

    const int t = threadIdx.x;
    const int f = blockIdx.x * BLKA + t;

    if (t < MAXB2) { h[t] = 0; lfill[t] = 0; }
    for (int i = t; i < 3 * BLKA; i += BLKA) sbuck[i] = 0xFF;
    __syncthreads();

    const bool on = (f < F);
    int i0 = 0, i1 = 0, i2 = 0;
    float nx = 0, ny = 0, nz = 0, txv = 0, tyv = 0, tzv = 0;

    if (on) {
        i0 = faces[3 * f + 0]; i1 = faces[3 * f + 1]; i2 = faces[3 * f + 2];

        const float p0x = pos[3*i0+0], p0y = pos[3*i0+1], p0z = pos[3*i0+2];
        const float p1x = pos[3*i1+0], p1y = pos[3*i1+1], p1z = pos[3*i1+2];
        const float p2x = pos[3*i2+0], p2y = pos[3*i2+1], p2z = pos[3*i2+2];

        const float e1x = p1x - p0x, e1y = p1y - p0y, e1z = p1z - p0z;
        const float e2x = p2x - p0x, e2y = p2y - p0y, e2z = p2z - p0z;

        nx = e1y * e2z - e1z * e2y;
        ny = e1z * e2x - e1x * e2z;
        nz = e1x * e2y - e1y * e2x;

        const int t0 = uvf[3 * f + 0];
        const int t1 = uvf[3 * f + 1];
        const int t2 = uvf[3 * f + 2];

        const float u0x = tex[2*t0+0], u0y = tex[2*t0+1];
        const float u1x = tex[2*t1+0], u1y = tex[2*t1+1];
        const float u2x = tex[2*t2+0], u2y = tex[2*t2+1];

        const float d1x = u1x - u0x, d1y = u1y - u0y;
        const float d2x = u2x - u0x, d2y = u2y - u0y;

        float denom = d1x * d2y - d1y * d2x;
        denom = (denom > 0.0f) ? fmaxf(denom, EPS_DENOM) : fminf(denom, -EPS_DENOM);
        const float inv = 1.0f / denom;

        txv = (e1x * d2y - e2x * d1y) * inv;
        tyv = (e1y * d2y - e2y * d1y) * inv;
        tzv = (e1z * d2y - e2z * d1y) * inv;

        float* fd = &face_data[(size_t)f * FST];
        reinterpret_cast<float2*>(fd)[0] = make_float2(nx, ny);
        reinterpret_cast<float2*>(fd)[1] = make_float2(nz, txv);
        reinterpret_cast<float2*>(fd)[2] = make_float2(tyv, tzv);

        atomicAdd(&h[i0 >> CB2_LOG], 1);
        atomicAdd(&h[i1 >> CB2_LOG], 1);
        atomicAdd(&h[i2 >> CB2_LOG], 1);
    }
    __syncthreads();

    if (t < MAXB2) sc[t] = h[t];
    __syncthreads();
    for (int d = 1; d < MAXB2; d <<= 1) {
        int v2 = 0;
        if (t < MAXB2) v2 = sc[t] + ((t >= d) ? sc[t - d] : 0);
        __syncthreads();
        if (t < MAXB2) sc[t] = v2;
        __syncthreads();
    }
    if (t < MAXB2) {
        loff[t] = sc[t] - h[t];
        const int cnt = h[t];
        int gb = -1;
        if (t < NBC && cnt > 0) {
            gb = atomicAdd(&cursors[t], cnt);
            if (gb + cnt <= CAP2) atomicMax(&validw[t], gb + cnt);
            else gb = -1;
        }
        gbase[t] = gb;
    }
    __syncthreads();

    if (on) {
        const int vi[3] = { i0, i1, i2 };
#pragma unroll
        for (int c = 0; c < 3; ++c) {
            const int v = vi[c];
            const int b = v >> CB2_LOG;
            if (gbase[b] >= 0) {
                const int slot = atomicAdd(&lfill[b], 1);
                const int p = loff[b] + slot;
                sface[p] = (unsigned)f;
                svloc[p] = (unsigned short)(v & (CB2 - 1));
                sbuck[p] = (unsigned char)b;
            } else {
                atomicAdd(&nacc[3*v+0], nx);
                atomicAdd(&nacc[3*v+1], ny);
                atomicAdd(&nacc[3*v+2], nz);
                atomicAdd(&tacc[3*v+0], txv);
                atomicAdd(&tacc[3*v+1], tyv);
                atomicAdd(&tacc[3*v+2], tzv);
            }
        }
    }
    __syncthreads();

    for (int i = t; i < 3 * BLKA; i += BLKA) {
        const unsigned b = sbuck[i];
        if (b != 0xFFu) {
            const int g = gbase[b] + (i - loff[b]);
            const size_t base = (size_t)b * CAP2;
            ef[base + g] = sface[i];
            ev[base + g] = svloc[i];
        }
    }
}

__global__ __launch_bounds__(BLKA)
void vg_bucket_reduce3(const float* __restrict__ face_data,
                       const unsigned* __restrict__ ef,
                       const unsigned short* __restrict__ ev,
                       const int* __restrict__ validw,
                       float* __restrict__ nacc, float* __restrict__ tacc,
                       int V)
{
    __shared__ float acc[QSIZE * 6];   // 48 KB
    const int b = blockIdx.x;
    const int t = threadIdx.x;
    int count = validw[b];
    if (count > CAP2) count = CAP2;
    const size_t ebase = (size_t)b * CAP2;
    const int vbase = b << CB2_LOG;

    for (int q = 0; q < 4; ++q) {
        for (int i = t; i < QSIZE * 6; i += BLKA) acc[i] = 0.0f;
        __syncthreads();

        for (int e = t; e < count; e += BLKA) {
            const int vloc = (int)ev[ebase + e];
            if ((vloc >> QLOG) == q) {
                const unsigned f = ef[ebase + e];
                const float* fd = &face_data[(size_t)f * FST];
                const float2 a0 = reinterpret_cast<const float2*>(fd)[0];
                const float2 a1 = reinterpret_cast<const float2*>(fd)[1];
                const float2 a2 = reinterpret_cast<const float2*>(fd)[2];
                float* a = &acc[(vloc & (QSIZE - 1)) * 6];
                atomicAdd(a + 0, a0.x);
                atomicAdd(a + 1, a0.y);
                atomicAdd(a + 2, a1.x);
                atomicAdd(a + 3, a1.y);
                atomicAdd(a + 4, a2.x);
                atomicAdd(a + 5, a2.y);
            }
        }
        __syncthreads();

        for (int i = t; i < QSIZE; i += BLKA) {
            const int v = vbase + (q << QLOG) + i;
            if (v < V) {
                float nx = nacc[3*v+0] + acc[i*6+0];
                float ny = nacc[3*v+1] + acc[i*6+1];
                float nz = nacc[3*v+2] + acc[i*6+2];
                float tx = tacc[3*v+0] + acc[i*6+3];
                float ty = tacc[3*v+1] + acc[i*6+4];
                float tz = tacc[3*v+2] + acc[i*6+5];

                const float nd = nx*nx + ny*ny + nz*nz;
                if (nd > EPS_LEN) {
                    const float invn = 1.0f / sqrtf(nd);
                    nx *= invn; ny *= invn; nz *= invn;
                } else {
                    nx = 0.0f; ny = 0.0f; nz = 1.0f;
                }

                const float td = tx*tx + ty*ty + tz*tz;
                const float invt = 1.0f / sqrtf(fmaxf(td, EPS_LEN));
                tx *= invt; ty *= invt; tz *= invt;

                const float dp = tx*nx + ty*ny + tz*nz;
                tx -= dp * nx; ty -= dp * ny; tz -= dp * nz;

                const float td2 = tx*tx + ty*ty + tz*tz;
                const float invt2 = 1.0f / sqrtf(fmaxf(td2, EPS_LEN));
                tx *= invt2; ty *= invt2; tz *= invt2;

                nacc[3*v+0] = nx; nacc[3*v+1] = ny; nacc[3*v+2] = nz;
                tacc[3*v+0] = tx; tacc[3*v+1] = ty; tacc[3*v+2] = tz;
            }
        }
        __syncthreads();
    }
}

// ===========================================================================
// TIER 3: global-atomic fallback.
// ===========================================================================
__global__ void vg_face_kernel(const float* __restrict__ pos,
                               const int*   __restrict__ faces,
                               const float* __restrict__ tex,
                               const int*   __restrict__ uvf,
                               float* __restrict__ nacc,
                               float* __restrict__ tacc,
                               int F) {
    int f = blockIdx.x * blockDim.x + threadIdx.x;
    if (f >= F) return;

    const int i0 = faces[3*f+0], i1 = faces[3*f+1], i2 = faces[3*f+2];

    const float p0x = pos[3*i0+0], p0y = pos[3*i0+1], p0z = pos[3*i0+2];
    const float p1x = pos[3*i1+0], p1y = pos[3*i1+1], p1z = pos[3*i1+2];
    const float p2x = pos[3*i2+0], p2y = pos[3*i2+1], p2z = pos[3*i2+2];

    const float e1x = p1x - p0x, e1y = p1y - p0y, e1z = p1z - p0z;
    const float e2x = p2x - p0x, e2y = p2y - p0y, e2z = p2z - p0z;

    const float nx = e1y*e2z - e1z*e2y;
    const float ny = e1z*e2x - e1x*e2z;
    const float nz = e1x*e2y - e1y*e2x;

    const int t0 = uvf[3*f+0], t1 = uvf[3*f+1], t2 = uvf[3*f+2];

    const float u0x = tex[2*t0+0], u0y = tex[2*t0+1];
    const float u1x = tex[2*t1+0], u1y = tex[2*t1+1];
    const float u2x = tex[2*t2+0], u2y = tex[2*t2+1];

    const float d1x = u1x - u0x, d1y = u1y - u0y;
    const float d2x = u2x - u0x, d2y = u2y - u0y;

    float denom = d1x * d2y - d1y * d2x;
    denom = (denom > 0.0f) ? fmaxf(denom, EPS_DENOM) : fminf(denom, -EPS_DENOM);
    const float inv = 1.0f / denom;

    const float tx = (e1x*d2y - e2x*d1y) * inv;
    const float ty = (e1y*d2y - e2y*d1y) * inv;
    const float tz = (e1z*d2y - e2z*d1y) * inv;

    atomicAdd(&nacc[3*i0+0], nx); atomicAdd(&nacc[3*i0+1], ny); atomicAdd(&nacc[3*i0+2], nz);
    atomicAdd(&nacc[3*i1+0], nx); atomicAdd(&nacc[3*i1+1], ny); atomicAdd(&nacc[3*i1+2], nz);
    atomicAdd(&nacc[3*i2+0], nx); atomicAdd(&nacc[3*i2+1], ny); atomicAdd(&nacc[3*i2+2], nz);
    atomicAdd(&tacc[3*i0+0], tx); atomicAdd(&tacc[3*i0+1], ty); atomicAdd(&tacc[3*i0+2], tz);
    atomicAdd(&tacc[3*i1+0], tx); atomicAdd(&tacc[3*i1+1], ty); atomicAdd(&tacc[3*i1+2], tz);
    atomicAdd(&tacc[3*i2+0], tx); atomicAdd(&tacc[3*i2+1], ty); atomicAdd(&tacc[3*i2+2], tz);
}

__global__ void vg_finalize_kernel(float* __restrict__ nacc,
                                   float* __restrict__ tacc,
                                   int V) {
    int v = blockIdx.x * blockDim.x + threadIdx.x;
    if (v >= V) return;

    float nx = nacc[3*v+0], ny = nacc[3*v+1], nz = nacc[3*v+2];
    float nd = nx*nx + ny*ny + nz*nz;
    if (nd > EPS_LEN) {
        const float invn = 1.0f / sqrtf(nd);
        nx *= invn; ny *= invn; nz *= invn;
    } else {
        nx = 0.0f; ny = 0.0f; nz = 1.0f;
    }

    float tx = tacc[3*v+0], ty = tacc[3*v+1], tz = tacc[3*v+2];
    float td = tx*tx + ty*ty + tz*tz;
    float invt = 1.0f / sqrtf(fmaxf(td, EPS_LEN));
    tx *= invt; ty *= invt; tz *= invt;
    const float dp = tx*nx + ty*ny + tz*nz;
    tx -= dp*nx; ty -= dp*ny; tz -= dp*nz;
    float td2 = tx*tx + ty*ty + tz*tz;
    float invt2 = 1.0f / sqrtf(fmaxf(td2, EPS_LEN));
    tx *= invt2; ty *= invt2; tz *= invt2;

    nacc[3*v+0] = nx; nacc[3*v+1] = ny; nacc[3*v+2] = nz;
    tacc[3*v+0] = tx; tacc[3*v+1] = ty; tacc[3*v+2] = tz;
}

extern "C" void kernel_launch(void* const* d_in, const int* in_sizes, int n_in,
                              void* d_out, int out_size, void* d_ws, size_t ws_size,
                              hipStream_t stream) {
    const float* pos   = (const float*)d_in[0];
    const int*   faces = (const int*)  d_in[1];
    const float* tex   = (const float*)d_in[2];
    const int*   uvf   = (const int*)  d_in[3];

    const int V = in_sizes[0] / 3;
    const int F = in_sizes[1] / 3;

    float* out  = (float*)d_out;
    float* nacc = out;
    float* tacc = out + (size_t)3 * V;

    hipMemsetAsync(d_out, 0, (size_t)out_size * sizeof(float), stream);

    // ---- tier 1: fine buckets + packed u32 entries ----
    const int NBC1 = (V + CBF - 1) >> CBF_LOG;
    {
        const size_t face_b = ((size_t)F * FST * sizeof(float) + 255) & ~(size_t)255;
        const size_t E_b    = ((size_t)NBC1 * CAPF * sizeof(unsigned) + 255) & ~(size_t)255;
        const size_t cur_b  = ((size_t)NBC1 * sizeof(int) + 255) & ~(size_t)255;
        const size_t need1  = face_b + E_b + 2 * cur_b + 256;

        if (ws_size >= need1 && NBC1 <= NBCP && F <= (1 << 22)) {
            char* ws = (char*)d_ws;
            float*    face_data = (float*)ws;    ws += face_b;
            unsigned* E         = (unsigned*)ws; ws += E_b;
            int*      cursors   = (int*)ws;      ws += cur_b;
            int*      validw    = (int*)ws;

            hipMemsetAsync(cursors, 0, cur_b, stream);
            hipMemsetAsync(validw,  0, cur_b, stream);

            vg_face_bin_f<<<(F + BLKA - 1) / BLKA, BLKA, 0, stream>>>(
                pos, faces, tex, uvf, face_data, E, cursors, validw,
                nacc, tacc, F, NBC1);
            vg_gather_reduce_f<<<NBC1, 512, 0, stream>>>(
                face_data, E, validw, nacc, tacc, V);
            return;
        }
    }

    // ---- tier 2: round-3 proven path ----
    const int NBC2 = (V + CB2 - 1) >> CB2_LOG;
    {
        const size_t NE2    = (size_t)NBC2 * CAP2;
        const size_t face_b = ((size_t)F * FST * sizeof(float) + 255) & ~(size_t)255;
        const size_t ef_b   = (NE2 * 4 + 255) & ~(size_t)255;
        const size_t ev2_b  = (NE2 * 2 + 255) & ~(size_t)255;
        const size_t cur_b  = ((size_t)NBC2 * sizeof(int) + 255) & ~(size_t)255;
        const size_t need2  = face_b + ef_b + ev2_b + 2 * cur_b + 256;

        if (ws_size >= need2 && NBC2 <= 255 && F < (1 << 22)) {
            char* ws = (char*)d_ws;
            float*          face_data = (float*)ws;          ws += face_b;
            unsigned*       ef        = (unsigned*)ws;       ws += ef_b;
            unsigned short* ev        = (unsigned short*)ws; ws += ev2_b;
            int*            cursors   = (int*)ws;            ws += cur_b;
            int*            validw    = (int*)ws;

            hipMemsetAsync(cursors, 0, cur_b, stream);
            hipMemsetAsync(validw,  0, cur_b, stream);

            vg_face_bin3<<<(F + BLKA - 1) / BLKA, BLKA, 0, stream>>>(
                pos, faces, tex, uvf, face_data, ef, ev, cursors, validw,
                nacc, tacc, F, NBC2);
            vg_bucket_reduce3<<<NBC2, BLKA, 0, stream>>>(
                face_data, ef, ev, validw, nacc, tacc, V);
            return;
        }
    }

    // ---- tier 3: global atomics ----
    const int BLK = 256;
    vg_face_kernel<<<(F + BLK - 1) / BLK, BLK, 0, stream>>>(pos, faces, tex, uvf,
                                                            nacc, tacc, F);
    vg_finalize_kernel<<<(V + BLK - 1) / BLK, BLK, 0, stream>>>(nacc, tacc, V);
}